// Round 1
// baseline (1317.926 us; speedup 1.0000x reference)
//
#include <hip/hip_runtime.h>
#include <stdint.h>

#define N_ROWS 262144
#define D_DIM  1024
#define H_DIM  512
#define N_SEG  512

typedef __attribute__((ext_vector_type(4))) float  f32x4;
typedef __attribute__((ext_vector_type(8))) __bf16 bf16x8;
typedef __attribute__((ext_vector_type(8))) unsigned short ushort8;

static __device__ __forceinline__ unsigned short f2bf(float f) {
  union { float f; uint32_t u; } c; c.f = f;
  return (unsigned short)((c.u + 0x7FFFu + ((c.u >> 16) & 1u)) >> 16);  // RNE
}

static __device__ __forceinline__ float fast_tanh(float u) {
  // tanh(u) = 1 - 2/(e^{2u}+1); correct limits at +/-inf of the exp
  return 1.0f - 2.0f / (__expf(2.0f * u) + 1.0f);
}

// ---------------- kernel 0: W1,W2 f32 -> bf16 ----------------
__global__ void cvt_w(const float* __restrict__ W1, const float* __restrict__ W2,
                      unsigned short* __restrict__ wbf) {
  int idx = blockIdx.x * 256 + threadIdx.x;            // 0 .. 2*H*D-1
  if (idx < H_DIM * D_DIM) wbf[idx] = f2bf(W1[idx]);
  else                     wbf[idx] = f2bf(W2[idx - H_DIM * D_DIM]);
}

// ---------------- kernel 1: a[i] = (tanh(xW1^T) * softmax(xW2^T)) @ W3^T ----
// 64 rows/block in swizzled bf16 LDS; 8 waves = 8 col-slices of 64 (full H).
// B-frags read straight from L2-resident bf16 W (2 MB/block, minimal).
__launch_bounds__(512, 2)
__global__ void alpha_kernel(const float* __restrict__ x,
                             const unsigned short* __restrict__ wbf,
                             const float* __restrict__ W3,
                             float* __restrict__ a_out)
{
  extern __shared__ unsigned char lds[];       // 131072 (x tile) + 6144 (reduce)
  const int tid  = threadIdx.x;
  const int lane = tid & 63;
  const int wid  = tid >> 6;                   // 0..7  -> col slice wid*64
  const int l15  = lane & 15;
  const int lg   = lane >> 4;                  // 0..3
  const int row0 = blockIdx.x << 6;

  // ---- stage x tile: 64x1024 f32 -> bf16, XOR-swizzled rows ----
  for (int it = 0; it < 16; ++it) {
    int c  = (it << 9) + tid;                  // chunk id, 8 bf16 each
    int r  = c >> 7;                           // row 0..63
    int c8 = c & 127;                          // chunk in row
    const float* src = x + ((size_t)(row0 + r) << 10) + (c8 << 3);
    f32x4 f0 = *(const f32x4*)src;
    f32x4 f1 = *(const f32x4*)(src + 4);
    ushort8 v;
    v[0]=f2bf(f0[0]); v[1]=f2bf(f0[1]); v[2]=f2bf(f0[2]); v[3]=f2bf(f0[3]);
    v[4]=f2bf(f1[0]); v[5]=f2bf(f1[1]); v[6]=f2bf(f1[2]); v[7]=f2bf(f1[3]);
    uint32_t byte = ((uint32_t)(r << 11) + (uint32_t)(c8 << 4)) ^ ((uint32_t)(r & 7) << 4);
    *(ushort8*)(lds + byte) = v;
  }
  __syncthreads();

  const unsigned short* Wb1 = wbf;
  const unsigned short* Wb2 = wbf + (H_DIM * D_DIM);
  uint32_t woff[4];
  #pragma unroll
  for (int cf = 0; cf < 4; ++cf)
    woff[cf] = (uint32_t)((((wid << 6) + (cf << 4) + l15) << 10) + (lg << 3));

  f32x4 au[4][4], av[4][4];
  #pragma unroll
  for (int rf = 0; rf < 4; ++rf)
    #pragma unroll
    for (int cf = 0; cf < 4; ++cf) {
      au[rf][cf] = (f32x4){0.f,0.f,0.f,0.f};
      av[rf][cf] = (f32x4){0.f,0.f,0.f,0.f};
    }

  const uint32_t abase = ((uint32_t)l15 << 11) + ((uint32_t)lg << 4);
  const uint32_t swz   = ((uint32_t)(l15 & 7)) << 4;

  bf16x8 bA1[4], bA2[4], bB1[4], bB2[4];
  #pragma unroll
  for (int cf = 0; cf < 4; ++cf) {
    bA1[cf] = *(const bf16x8*)(Wb1 + woff[cf]);
    bA2[cf] = *(const bf16x8*)(Wb2 + woff[cf]);
  }

  for (int kk = 0; kk < 32; kk += 2) {
    #pragma unroll
    for (int cf = 0; cf < 4; ++cf) {           // prefetch kk+1
      bB1[cf] = *(const bf16x8*)(Wb1 + woff[cf] + ((kk + 1) << 5));
      bB2[cf] = *(const bf16x8*)(Wb2 + woff[cf] + ((kk + 1) << 5));
    }
    bf16x8 afr[4];
    #pragma unroll
    for (int rf = 0; rf < 4; ++rf)
      afr[rf] = *(const bf16x8*)(lds + (((uint32_t)(rf << 15) + abase + (uint32_t)(kk << 6)) ^ swz));
    #pragma unroll
    for (int cf = 0; cf < 4; ++cf)
      #pragma unroll
      for (int rf = 0; rf < 4; ++rf) {
        au[rf][cf] = __builtin_amdgcn_mfma_f32_16x16x32_bf16(afr[rf], bA1[cf], au[rf][cf], 0, 0, 0);
        av[rf][cf] = __builtin_amdgcn_mfma_f32_16x16x32_bf16(afr[rf], bA2[cf], av[rf][cf], 0, 0, 0);
      }
    if (kk + 2 < 32) {
      #pragma unroll
      for (int cf = 0; cf < 4; ++cf) {         // prefetch kk+2
        bA1[cf] = *(const bf16x8*)(Wb1 + woff[cf] + ((kk + 2) << 5));
        bA2[cf] = *(const bf16x8*)(Wb2 + woff[cf] + ((kk + 2) << 5));
      }
    }
    bf16x8 af2[4];
    #pragma unroll
    for (int rf = 0; rf < 4; ++rf)
      af2[rf] = *(const bf16x8*)(lds + (((uint32_t)(rf << 15) + abase + (uint32_t)((kk + 1) << 6)) ^ swz));
    #pragma unroll
    for (int cf = 0; cf < 4; ++cf)
      #pragma unroll
      for (int rf = 0; rf < 4; ++rf) {
        au[rf][cf] = __builtin_amdgcn_mfma_f32_16x16x32_bf16(af2[rf], bB1[cf], au[rf][cf], 0, 0, 0);
        av[rf][cf] = __builtin_amdgcn_mfma_f32_16x16x32_bf16(af2[rf], bB2[cf], av[rf][cf], 0, 0, 0);
      }
  }

  // ---- epilogue: per-wave partial softmax stats over its 64 cols ----
  float w3v[4];
  #pragma unroll
  for (int cf = 0; cf < 4; ++cf) w3v[cf] = W3[(wid << 6) + (cf << 4) + l15];

  float* redm = (float*)(lds + 131072);
  float* reds = redm + 512;
  float* redn = redm + 1024;

  #pragma unroll
  for (int rf = 0; rf < 4; ++rf) {
    float mx[4], sj[4], nj[4];
    #pragma unroll
    for (int j = 0; j < 4; ++j)
      mx[j] = fmaxf(fmaxf(av[rf][0][j], av[rf][1][j]), fmaxf(av[rf][2][j], av[rf][3][j]));
    #pragma unroll
    for (int d = 1; d < 16; d <<= 1)
      #pragma unroll
      for (int j = 0; j < 4; ++j) mx[j] = fmaxf(mx[j], __shfl_xor(mx[j], d));
    #pragma unroll
    for (int j = 0; j < 4; ++j) { sj[j] = 0.f; nj[j] = 0.f; }
    #pragma unroll
    for (int cf = 0; cf < 4; ++cf)
      #pragma unroll
      for (int j = 0; j < 4; ++j) {
        float p  = __expf(av[rf][cf][j] - mx[j]);
        float tt = fast_tanh(au[rf][cf][j]);
        sj[j] += p;
        nj[j] += tt * p * w3v[cf];
      }
    #pragma unroll
    for (int d = 1; d < 16; d <<= 1)
      #pragma unroll
      for (int j = 0; j < 4; ++j) {
        sj[j] += __shfl_xor(sj[j], d);
        nj[j] += __shfl_xor(nj[j], d);
      }
    if (l15 == 0) {
      #pragma unroll
      for (int j = 0; j < 4; ++j) {
        int r = (rf << 4) + (lg << 2) + j;
        redm[(wid << 6) + r] = mx[j];
        reds[(wid << 6) + r] = sj[j];
        redn[(wid << 6) + r] = nj[j];
      }
    }
  }
  __syncthreads();
  if (tid < 64) {
    float m = redm[tid];
    #pragma unroll
    for (int wv = 1; wv < 8; ++wv) m = fmaxf(m, redm[(wv << 6) + tid]);
    float s = 0.f, n = 0.f;
    #pragma unroll
    for (int wv = 0; wv < 8; ++wv) {
      float sc = __expf(redm[(wv << 6) + tid] - m);
      s += reds[(wv << 6) + tid] * sc;
      n += redn[(wv << 6) + tid] * sc;
    }
    a_out[row0 + tid] = n / s;
  }
}

// ---------------- kernel 2: segment softmax weights ----------------
static __device__ __forceinline__ int lower_bound(const int* __restrict__ batch, int key) {
  int lo = 0, hi = N_ROWS;
  while (lo < hi) { int mid = (lo + hi) >> 1; if (batch[mid] < key) lo = mid + 1; else hi = mid; }
  return lo;
}

__global__ void seg_kernel(const float* __restrict__ a, const int* __restrict__ batch,
                           float* __restrict__ w) {
  __shared__ float sm[8];
  int b = blockIdx.x;
  int start = lower_bound(batch, b);
  int end   = lower_bound(batch, b + 1);
  int tid = threadIdx.x;

  float m = -3.4e38f;
  for (int i = start + tid; i < end; i += 256) m = fmaxf(m, a[i]);
  for (int d = 1; d < 64; d <<= 1) m = fmaxf(m, __shfl_xor(m, d));
  if ((tid & 63) == 0) sm[tid >> 6] = m;
  __syncthreads();
  m = fmaxf(fmaxf(sm[0], sm[1]), fmaxf(sm[2], sm[3]));

  float s = 0.f;
  for (int i = start + tid; i < end; i += 256) s += __expf(a[i] - m);
  for (int d = 1; d < 64; d <<= 1) s += __shfl_xor(s, d);
  if ((tid & 63) == 0) sm[4 + (tid >> 6)] = s;
  __syncthreads();
  s = sm[4] + sm[5] + sm[6] + sm[7];

  float rinv = 1.0f / s;
  for (int i = start + tid; i < end; i += 256) w[i] = __expf(a[i] - m) * rinv;
}

// ---------------- kernel 3: z[b] = sum_i w_i * x_i ----------------
__global__ void z_kernel(const float* __restrict__ x, const float* __restrict__ w,
                         const int* __restrict__ batch, float* __restrict__ z) {
  int b = blockIdx.x >> 2, part = blockIdx.x & 3;
  int start = lower_bound(batch, b);
  int end   = lower_bound(batch, b + 1);
  int len = end - start;
  int ps = start + ((len * part) >> 2);
  int pe = start + ((len * (part + 1)) >> 2);
  int col = threadIdx.x << 2;

  f32x4 acc = (f32x4){0.f, 0.f, 0.f, 0.f};
  for (int i = ps; i < pe; ++i) {
    f32x4 xv = *(const f32x4*)(x + ((size_t)i << 10) + col);
    float wi = w[i];
    acc += xv * wi;
  }
  float* zp = z + ((size_t)b << 10) + col;
  atomicAdd(zp + 0, acc[0]);
  atomicAdd(zp + 1, acc[1]);
  atomicAdd(zp + 2, acc[2]);
  atomicAdd(zp + 3, acc[3]);
}

// ---------------- launch ----------------
extern "C" void kernel_launch(void* const* d_in, const int* in_sizes, int n_in,
                              void* d_out, int out_size, void* d_ws, size_t ws_size,
                              hipStream_t stream) {
  const float* x     = (const float*)d_in[0];
  const int*   batch = (const int*)d_in[1];
  const float* W1    = (const float*)d_in[2];
  const float* W2    = (const float*)d_in[3];
  const float* W3    = (const float*)d_in[4];
  float* z = (float*)d_out;

  // ws layout: [0,2MB) W1|W2 bf16 ; [2MB,3MB) a[N] f32 ; [3MB,4MB) w[N] f32
  unsigned short* wbf = (unsigned short*)d_ws;
  float* a = (float*)((char*)d_ws + (2u << 20));
  float* w = (float*)((char*)d_ws + (3u << 20));

  hipMemsetAsync(d_out, 0, (size_t)N_SEG * D_DIM * sizeof(float), stream);

  cvt_w<<<(2 * H_DIM * D_DIM) / 256, 256, 0, stream>>>(W1, W2, wbf);

  const int ldsBytes = 131072 + 6144;
  hipFuncSetAttribute(reinterpret_cast<const void*>(alpha_kernel),
                      hipFuncAttributeMaxDynamicSharedMemorySize, ldsBytes);
  alpha_kernel<<<N_ROWS / 64, 512, ldsBytes, stream>>>(x, wbf, W3, a);

  seg_kernel<<<N_SEG, 256, 0, stream>>>(a, batch, w);

  z_kernel<<<N_SEG * 4, 256, 0, stream>>>(x, w, batch, z);
}